// Round 4
// baseline (678.577 us; speedup 1.0000x reference)
//
#include <hip/hip_runtime.h>
#include <hip/hip_bf16.h>

// ---------------------------------------------------------------------------
// RWKV TimeMix:  k = x Wk^T ; r = x Wr^T ; v = r ; y = wkv(w,u,k,v)
//                out = (sigmoid(r) * y) Wo^T
// B=16, T=1024, C=1024.  ALL inputs and the output are FLOAT32 (per the
// reference — R0-R3 mis-cast them as bf16, which is why every round NaN'd:
// fp32 bit patterns read as bf16 contain ~0.4% NaN/Inf).
//
// Compute plan: cast x/Wk/Wr/Wo to bf16 once (fp32 MFMA doesn't exist on
// CDNA4), run bf16-MFMA GEMMs with fp32 accumulate, fp32 final epilogue.
//
// Memory plan:
//   ws:    [xb 32 MiB][Wkb 2][Wrb 2][Wob 2]  (38 MiB total; sy reuses xb)
//   d_out: 64 MiB fp32 — mid-pipeline holds k(bf16) in the low 32 MiB and
//          r(bf16) in the high 32 MiB; finally overwritten with fp32 out.
//   gemm3 reads sy from ws (xb slot), so it never reads what it writes.
// ---------------------------------------------------------------------------

typedef __attribute__((ext_vector_type(8))) short bf16x8;   // 8 bf16 = 4 VGPRs
typedef __attribute__((ext_vector_type(4))) float f32x4;    // MFMA C/D
typedef __attribute__((ext_vector_type(4))) unsigned int u32x4;

#define BM 128
#define BN 128
#define BK 32

// ---- fp32 -> bf16 cast, 4 elements/thread ---------------------------------
__global__ __launch_bounds__(256) void cast_f32_bf16_kernel(
    const float* __restrict__ src, __hip_bfloat16* __restrict__ dst, int n)
{
    const int i = (blockIdx.x * 256 + threadIdx.x) * 4;
    if (i + 3 < n) {
        const f32x4 v = *(const f32x4*)(src + i);
        __hip_bfloat16 o[4];
        o[0] = __float2bfloat16(v[0]);
        o[1] = __float2bfloat16(v[1]);
        o[2] = __float2bfloat16(v[2]);
        o[3] = __float2bfloat16(v[3]);
        *(__attribute__((ext_vector_type(4))) short*)(dst + i) =
            *(__attribute__((ext_vector_type(4))) short*)o;
    }
}

// ---- C[m, bn+n] = sum_k A[m,k] * Bt[n,k]  (A,Bt bf16; OutT fp32 or bf16) --
template <typename OutT>
__global__ __launch_bounds__(256) void gemm_bt_kernel(
    const __hip_bfloat16* __restrict__ A,
    const __hip_bfloat16* __restrict__ Bt,
    OutT* __restrict__ C,
    int K, int ldc)
{
    __shared__ __align__(16) __hip_bfloat16 As[BM * BK];   // 8 KiB
    __shared__ __align__(16) __hip_bfloat16 Bs[BN * BK];   // 8 KiB

    const int tid = threadIdx.x;
    const int bm  = blockIdx.x * BM;
    const int bn  = blockIdx.y * BN;

    const int wave = tid >> 6;
    const int lane = tid & 63;
    const int wm   = (wave & 1) * 64;
    const int wn   = (wave >> 1) * 64;
    const int nl   = lane & 15;
    const int quad = lane >> 4;

    f32x4 acc[4][4] = {};

    // Staging: LDS tile row-major [128][32] bf16 (row = 64 B). Thread tid
    // owns 16 B at offsets tid*16 (rows 0..63) and tid*16+4096 (rows 64..127).
    const int r0 = tid >> 2;            // 0..63
    const int cb = (tid & 3) * 16;      // 0,16,32,48
    const int o0 = tid * 16;
    const int o1 = o0 + 4096;

    const size_t rowb = (size_t)K * 2;
    const char* Ag0 = (const char*)A  + (size_t)(bm + r0) * rowb + cb;
    const char* Ag1 = Ag0 + 64 * rowb;
    const char* Bg0 = (const char*)Bt + (size_t)(bn + r0) * rowb + cb;
    const char* Bg1 = Bg0 + 64 * rowb;

    for (int kt = 0; kt < K; kt += BK) {
        const size_t kb = (size_t)kt * 2;
        const u32x4 a0 = *(const u32x4*)(Ag0 + kb);
        const u32x4 a1 = *(const u32x4*)(Ag1 + kb);
        const u32x4 b0 = *(const u32x4*)(Bg0 + kb);
        const u32x4 b1 = *(const u32x4*)(Bg1 + kb);

        __syncthreads();  // previous iteration's LDS reads complete
        *(u32x4*)((char*)As + o0) = a0;
        *(u32x4*)((char*)As + o1) = a1;
        *(u32x4*)((char*)Bs + o0) = b0;
        *(u32x4*)((char*)Bs + o1) = b1;
        __syncthreads();  // staging visible to all waves

        const __hip_bfloat16* Ab = As + (wm + nl) * BK + quad * 8;
        const __hip_bfloat16* Bb = Bs + (wn + nl) * BK + quad * 8;
        bf16x8 af[4], bfr[4];
#pragma unroll
        for (int i = 0; i < 4; ++i) af[i]  = *(const bf16x8*)(Ab + i * 16 * BK);
#pragma unroll
        for (int j = 0; j < 4; ++j) bfr[j] = *(const bf16x8*)(Bb + j * 16 * BK);
#pragma unroll
        for (int i = 0; i < 4; ++i)
#pragma unroll
            for (int j = 0; j < 4; ++j)
                acc[i][j] = __builtin_amdgcn_mfma_f32_16x16x32_bf16(
                    af[i], bfr[j], acc[i][j], 0, 0, 0);
    }

    // C/D layout (m89-verified): col = lane&15, row = quad*4 + reg.
#pragma unroll
    for (int i = 0; i < 4; ++i) {
#pragma unroll
        for (int j = 0; j < 4; ++j) {
            const int n = bn + wn + j * 16 + nl;
#pragma unroll
            for (int r = 0; r < 4; ++r) {
                const int m = bm + wm + i * 16 + quad * 4 + r;
                float vv = acc[i][j][r];
                if constexpr (__is_same(OutT, float))
                    C[(size_t)m * ldc + n] = vv;
                else
                    C[(size_t)m * ldc + n] = __float2bfloat16(vv);
            }
        }
    }
}

__device__ __forceinline__ float clampf(float x, float lo, float hi) {
    return fminf(fmaxf(x, lo), hi);   // NaN -> lo (maxNum semantics)
}

// ---- WKV scan + sigmoid gate; one thread per (b,c) channel ----------------
__global__ __launch_bounds__(64) void wkv_scan_kernel(
    const __hip_bfloat16* __restrict__ kbuf, // [M, C] = k   (bf16)
    const __hip_bfloat16* __restrict__ rbuf, // [M, C] = r=v (bf16)
    const float* __restrict__ tf,            // time_first (= u), fp32
    const float* __restrict__ td,            // time_decay (w = -exp(td)), fp32
    __hip_bfloat16* __restrict__ sy,         // out: sigmoid(r)*y (bf16)
    int T, int C)
{
    const int gid = blockIdx.x * 64 + threadIdx.x;   // 0 .. B*C-1
    const int b = gid / C;
    const int c = gid - b * C;

    const float u = clampf(tf[c], -80.f, 80.f);
    const float w = -__expf(clampf(td[c], -80.f, 10.f));

    float a = 0.f, bb = 0.f, pp = -1e38f;

    const __hip_bfloat16* kp = kbuf + (size_t)b * T * C + c;
    const __hip_bfloat16* rp = rbuf + (size_t)b * T * C + c;
    __hip_bfloat16* op = sy + (size_t)b * T * C + c;

    // Clamps are no-ops on correct data (|k|,|v| ~ 5); they keep any residual
    // garbage finite so a failure is diagnosable instead of NaN.
    float kt = clampf(__bfloat162float(kp[0]), -80.f, 80.f);
    float vt = clampf(__bfloat162float(rp[0]), -1e4f, 1e4f);

    for (int t = 0; t < T; ++t) {
        // distance-1 prefetch: loads issue before the long exp chain
        float ktn = 0.f, vtn = 0.f;
        if (t + 1 < T) {
            ktn = clampf(__bfloat162float(kp[(size_t)(t + 1) * C]), -80.f, 80.f);
            vtn = clampf(__bfloat162float(rp[(size_t)(t + 1) * C]), -1e4f, 1e4f);
        }

        const float ww = u + kt;
        const float q  = fmaxf(pp, ww);
        const float e1 = __expf(pp - q);
        const float e2 = __expf(ww - q);
        const float y  = (e1 * a + e2 * vt) / (e1 * bb + e2);
        const float sig = 1.f / (1.f + __expf(-vt));   // sigmoid(r), r == v
        op[(size_t)t * C] = __float2bfloat16(sig * y);

        const float ww2 = pp + w;
        const float q2  = fmaxf(ww2, kt);
        const float e1b = __expf(ww2 - q2);
        const float e2b = __expf(kt - q2);
        a  = e1b * a  + e2b * vt;
        bb = e1b * bb + e2b;
        pp = q2;

        kt = ktn; vt = vtn;
    }
}

extern "C" void kernel_launch(void* const* d_in, const int* in_sizes, int n_in,
                              void* d_out, int out_size, void* d_ws, size_t ws_size,
                              hipStream_t stream) {
    const float* x  = (const float*)d_in[0];
    const float* Wk = (const float*)d_in[1];
    const float* Wr = (const float*)d_in[2];
    const float* Wo = (const float*)d_in[3];
    const float* td = (const float*)d_in[4];
    const float* tf = (const float*)d_in[5];
    float* out = (float*)d_out;

    const int B = 16, T = 1024, C = 1024;
    const int M = B * T;                       // 16384
    const int MC = M * C;                      // 16,777,216
    const int CC = C * C;                      // 1,048,576

    // ws layout (bf16): xb [MC] | Wkb [CC] | Wrb [CC] | Wob [CC]   (38 MiB)
    __hip_bfloat16* xb  = (__hip_bfloat16*)d_ws;
    __hip_bfloat16* Wkb = xb + (size_t)MC;
    __hip_bfloat16* Wrb = Wkb + (size_t)CC;
    __hip_bfloat16* Wob = Wrb + (size_t)CC;
    __hip_bfloat16* sy  = xb;                  // reuses xb slot (xb dead)

    // d_out's 64 MiB mid-pipeline: k bf16 [MC] | r bf16 [MC]
    __hip_bfloat16* kbuf = (__hip_bfloat16*)d_out;
    __hip_bfloat16* rbuf = kbuf + (size_t)MC;

    // 1) casts fp32 -> bf16
    cast_f32_bf16_kernel<<<MC / 1024, 256, 0, stream>>>(x,  xb,  MC);
    cast_f32_bf16_kernel<<<CC / 1024, 256, 0, stream>>>(Wk, Wkb, CC);
    cast_f32_bf16_kernel<<<CC / 1024, 256, 0, stream>>>(Wr, Wrb, CC);
    cast_f32_bf16_kernel<<<CC / 1024, 256, 0, stream>>>(Wo, Wob, CC);

    // 2) k = xb Wkb^T -> d_out low half (bf16)
    gemm_bt_kernel<__hip_bfloat16><<<dim3(M / BM, C / BN), 256, 0, stream>>>(
        xb, Wkb, kbuf, C, C);

    // 3) r = xb Wrb^T -> d_out high half (bf16)
    gemm_bt_kernel<__hip_bfloat16><<<dim3(M / BM, C / BN), 256, 0, stream>>>(
        xb, Wrb, rbuf, C, C);

    // 4) scan + gate -> sy (ws, xb slot)
    wkv_scan_kernel<<<dim3((B * C) / 64), 64, 0, stream>>>(
        kbuf, rbuf, tf, td, sy, T, C);

    // 5) out = sy Wob^T -> d_out as fp32 (overwrites k/r; sy lives in ws)
    gemm_bt_kernel<float><<<dim3(M / BM, C / BN), 256, 0, stream>>>(
        sy, Wob, out, C, C);
}

// Round 5
// 368.846 us; speedup vs baseline: 1.8397x; 1.8397x over previous
//
#include <hip/hip_runtime.h>
#include <hip/hip_bf16.h>

// ---------------------------------------------------------------------------
// RWKV TimeMix:  k = x Wk^T ; r = x Wr^T ; v = r ; y = wkv(w,u,k,v)
//                out = (sigmoid(r) * y) Wo^T
// B=16, T=1024, C=1024.  All inputs and the output are FLOAT32.
//
// Compute plan: cast x/Wk/Wr/Wo to bf16 (no fp32 MFMA on CDNA4), bf16-MFMA
// GEMMs with fp32 accumulate, fp32 final epilogue.  WKV scan is fp32, log2-
// domain, 8-deep register prefetch (1 wave/CU -> pure latency machine).
//
// Memory plan:
//   ws:    [xb 32 MiB][Wkb 2][Wrb 2][Wob 2]  (38 MiB; sy reuses xb slot)
//   d_out: 64 MiB fp32 — mid-pipeline holds k(bf16) low half, r(bf16) high
//          half; finally overwritten with fp32 out (gemm3 reads sy from ws).
// ---------------------------------------------------------------------------

typedef __attribute__((ext_vector_type(8))) short bf16x8;   // 8 bf16 = 4 VGPRs
typedef __attribute__((ext_vector_type(4))) float f32x4;    // MFMA C/D
typedef __attribute__((ext_vector_type(4))) unsigned int u32x4;
typedef unsigned short u16;

#define BM 128
#define BN 128
#define BK 32

// ---- fp32 -> bf16 cast, 4 elements/thread ---------------------------------
__global__ __launch_bounds__(256) void cast_f32_bf16_kernel(
    const float* __restrict__ src, __hip_bfloat16* __restrict__ dst, int n)
{
    const int i = (blockIdx.x * 256 + threadIdx.x) * 4;
    if (i + 3 < n) {
        const f32x4 v = *(const f32x4*)(src + i);
        __hip_bfloat16 o[4];
        o[0] = __float2bfloat16(v[0]);
        o[1] = __float2bfloat16(v[1]);
        o[2] = __float2bfloat16(v[2]);
        o[3] = __float2bfloat16(v[3]);
        *(__attribute__((ext_vector_type(4))) short*)(dst + i) =
            *(__attribute__((ext_vector_type(4))) short*)o;
    }
}

// ---- C[m, bn+n] = sum_k A[m,k] * Bt[n,k]  (A,Bt bf16; OutT fp32 or bf16) --
template <typename OutT>
__global__ __launch_bounds__(256) void gemm_bt_kernel(
    const __hip_bfloat16* __restrict__ A,
    const __hip_bfloat16* __restrict__ Bt,
    OutT* __restrict__ C,
    int K, int ldc)
{
    __shared__ __align__(16) __hip_bfloat16 As[BM * BK];   // 8 KiB
    __shared__ __align__(16) __hip_bfloat16 Bs[BN * BK];   // 8 KiB

    const int tid = threadIdx.x;
    const int bm  = blockIdx.x * BM;
    const int bn  = blockIdx.y * BN;

    const int wave = tid >> 6;
    const int lane = tid & 63;
    const int wm   = (wave & 1) * 64;
    const int wn   = (wave >> 1) * 64;
    const int nl   = lane & 15;
    const int quad = lane >> 4;

    f32x4 acc[4][4] = {};

    const int r0 = tid >> 2;            // 0..63
    const int cb = (tid & 3) * 16;      // 0,16,32,48
    const int o0 = tid * 16;
    const int o1 = o0 + 4096;

    const size_t rowb = (size_t)K * 2;
    const char* Ag0 = (const char*)A  + (size_t)(bm + r0) * rowb + cb;
    const char* Ag1 = Ag0 + 64 * rowb;
    const char* Bg0 = (const char*)Bt + (size_t)(bn + r0) * rowb + cb;
    const char* Bg1 = Bg0 + 64 * rowb;

    for (int kt = 0; kt < K; kt += BK) {
        const size_t kb = (size_t)kt * 2;
        const u32x4 a0 = *(const u32x4*)(Ag0 + kb);
        const u32x4 a1 = *(const u32x4*)(Ag1 + kb);
        const u32x4 b0 = *(const u32x4*)(Bg0 + kb);
        const u32x4 b1 = *(const u32x4*)(Bg1 + kb);

        __syncthreads();
        *(u32x4*)((char*)As + o0) = a0;
        *(u32x4*)((char*)As + o1) = a1;
        *(u32x4*)((char*)Bs + o0) = b0;
        *(u32x4*)((char*)Bs + o1) = b1;
        __syncthreads();

        const __hip_bfloat16* Ab = As + (wm + nl) * BK + quad * 8;
        const __hip_bfloat16* Bb = Bs + (wn + nl) * BK + quad * 8;
        bf16x8 af[4], bfr[4];
#pragma unroll
        for (int i = 0; i < 4; ++i) af[i]  = *(const bf16x8*)(Ab + i * 16 * BK);
#pragma unroll
        for (int j = 0; j < 4; ++j) bfr[j] = *(const bf16x8*)(Bb + j * 16 * BK);
#pragma unroll
        for (int i = 0; i < 4; ++i)
#pragma unroll
            for (int j = 0; j < 4; ++j)
                acc[i][j] = __builtin_amdgcn_mfma_f32_16x16x32_bf16(
                    af[i], bfr[j], acc[i][j], 0, 0, 0);
    }

    // C/D layout (m89-verified): col = lane&15, row = quad*4 + reg.
#pragma unroll
    for (int i = 0; i < 4; ++i) {
#pragma unroll
        for (int j = 0; j < 4; ++j) {
            const int n = bn + wn + j * 16 + nl;
#pragma unroll
            for (int r = 0; r < 4; ++r) {
                const int m = bm + wm + i * 16 + quad * 4 + r;
                float vv = acc[i][j][r];
                if constexpr (__is_same(OutT, float))
                    C[(size_t)m * ldc + n] = vv;
                else
                    C[(size_t)m * ldc + n] = __float2bfloat16(vv);
            }
        }
    }
}

// ---------------------------------------------------------------------------
// WKV scan + sigmoid gate.  One thread per (b,c) channel, sequential over T.
// 1 wave/CU (parallelism = B*C = 16384 = 256 waves) -> latency is everything:
//  * 8-deep raw-u16 register prefetch (two ping-pong blocks, no dyn indexing)
//  * log2-domain math, ratio-form output (q cancels): 5 trans/iter total
// ---------------------------------------------------------------------------
#define L2E 1.4426950408889634f

struct Blk { u16 k[8]; u16 v[8]; };

__device__ __forceinline__ void load8(const u16* kp, const u16* vp,
                                      int t, int C, Blk& B) {
#pragma unroll
    for (int j = 0; j < 8; ++j) {
        B.k[j] = kp[(size_t)(t + j) * C];
        B.v[j] = vp[(size_t)(t + j) * C];
    }
}

__device__ __forceinline__ float bf2f(u16 r) {
    return __uint_as_float(((unsigned)r) << 16);
}

__device__ __forceinline__ void wkv_step(
    u16 kraw, u16 vraw, float u2, float w2,
    float& a, float& bb, float& pp2, __hip_bfloat16* op)
{
    const float kf = bf2f(kraw);
    const float vf = bf2f(vraw);
    const float k2 = kf * L2E;

    // output: y = (e1*a + e2*v)/(e1*bb + e2), divide through by e2 (q cancels)
    const float ww2 = u2 + k2;
    const float s   = __builtin_amdgcn_exp2f(fminf(pp2 - ww2, 60.f));
    const float num = s * a + vf;
    const float den = s * bb + 1.f;
    // gate: sigmoid(v) folded into a single reciprocal
    const float e   = __builtin_amdgcn_exp2f(-L2E * vf);
    const float res = num * __builtin_amdgcn_rcpf(den * (1.f + e));
    *op = __float2bfloat16(res);

    // state: d=(pp+w)-k (log2); e1b=2^min(d,0), e2b=2^(min(d,0)-d)
    const float d   = pp2 + w2 - k2;
    const float m0  = fminf(d, 0.f);
    const float e1b = __builtin_amdgcn_exp2f(m0);
    const float e2b = __builtin_amdgcn_exp2f(m0 - d);
    a   = e1b * a  + e2b * vf;
    bb  = e1b * bb + e2b;
    pp2 = k2 + fmaxf(d, 0.f);
}

__global__ __launch_bounds__(64) void wkv_scan_kernel(
    const __hip_bfloat16* __restrict__ kbuf, // [M, C] = k   (bf16)
    const __hip_bfloat16* __restrict__ rbuf, // [M, C] = r=v (bf16)
    const float* __restrict__ tf,            // time_first (= u), fp32
    const float* __restrict__ td,            // time_decay, fp32; w=-exp(td)
    __hip_bfloat16* __restrict__ sy,         // out: sigmoid(r)*y (bf16)
    int T, int C)
{
    const int gid = blockIdx.x * 64 + threadIdx.x;   // 0 .. B*C-1
    const int b = gid / C;
    const int c = gid - b * C;

    const float u2 = tf[c] * L2E;
    const float w2 = -__expf(td[c]) * L2E;

    float a = 0.f, bb = 0.f, pp2 = -1.4427e38f;      // (-1e38) * log2(e)

    const u16* kp = (const u16*)(kbuf + (size_t)b * T * C + c);
    const u16* vp = (const u16*)(rbuf + (size_t)b * T * C + c);
    __hip_bfloat16* op = sy + (size_t)b * T * C + c;

    Blk A, Bq;
    load8(kp, vp, 0, C, A);

    for (int tb = 0; tb < T; tb += 16) {
        load8(kp, vp, tb + 8, C, Bq);       // prefetch next 8 (always valid)
#pragma unroll
        for (int j = 0; j < 8; ++j)
            wkv_step(A.k[j], A.v[j], u2, w2, a, bb, pp2,
                     op + (size_t)(tb + j) * C);
        if (tb + 16 < T) load8(kp, vp, tb + 16, C, A);
#pragma unroll
        for (int j = 0; j < 8; ++j)
            wkv_step(Bq.k[j], Bq.v[j], u2, w2, a, bb, pp2,
                     op + (size_t)(tb + 8 + j) * C);
    }
}

extern "C" void kernel_launch(void* const* d_in, const int* in_sizes, int n_in,
                              void* d_out, int out_size, void* d_ws, size_t ws_size,
                              hipStream_t stream) {
    const float* x  = (const float*)d_in[0];
    const float* Wk = (const float*)d_in[1];
    const float* Wr = (const float*)d_in[2];
    const float* Wo = (const float*)d_in[3];
    const float* td = (const float*)d_in[4];
    const float* tf = (const float*)d_in[5];
    float* out = (float*)d_out;

    const int B = 16, T = 1024, C = 1024;
    const int M = B * T;                       // 16384
    const int MC = M * C;                      // 16,777,216
    const int CC = C * C;                      // 1,048,576

    // ws layout (bf16): xb [MC] | Wkb [CC] | Wrb [CC] | Wob [CC]   (38 MiB)
    __hip_bfloat16* xb  = (__hip_bfloat16*)d_ws;
    __hip_bfloat16* Wkb = xb + (size_t)MC;
    __hip_bfloat16* Wrb = Wkb + (size_t)CC;
    __hip_bfloat16* Wob = Wrb + (size_t)CC;
    __hip_bfloat16* sy  = xb;                  // reuses xb slot (xb dead)

    // d_out's 64 MiB mid-pipeline: k bf16 [MC] | r bf16 [MC]
    __hip_bfloat16* kbuf = (__hip_bfloat16*)d_out;
    __hip_bfloat16* rbuf = kbuf + (size_t)MC;

    // 1) casts fp32 -> bf16
    cast_f32_bf16_kernel<<<MC / 1024, 256, 0, stream>>>(x,  xb,  MC);
    cast_f32_bf16_kernel<<<CC / 1024, 256, 0, stream>>>(Wk, Wkb, CC);
    cast_f32_bf16_kernel<<<CC / 1024, 256, 0, stream>>>(Wr, Wrb, CC);
    cast_f32_bf16_kernel<<<CC / 1024, 256, 0, stream>>>(Wo, Wob, CC);

    // 2) k = xb Wkb^T -> d_out low half (bf16)
    gemm_bt_kernel<__hip_bfloat16><<<dim3(M / BM, C / BN), 256, 0, stream>>>(
        xb, Wkb, kbuf, C, C);

    // 3) r = xb Wrb^T -> d_out high half (bf16)
    gemm_bt_kernel<__hip_bfloat16><<<dim3(M / BM, C / BN), 256, 0, stream>>>(
        xb, Wrb, rbuf, C, C);

    // 4) scan + gate -> sy (ws, xb slot)
    wkv_scan_kernel<<<dim3((B * C) / 64), 64, 0, stream>>>(
        kbuf, rbuf, tf, td, sy, T, C);

    // 5) out = sy Wob^T -> d_out as fp32 (overwrites k/r; sy lives in ws)
    gemm_bt_kernel<float><<<dim3(M / BM, C / BN), 256, 0, stream>>>(
        sy, Wob, out, C, C);
}

// Round 6
// 353.142 us; speedup vs baseline: 1.9215x; 1.0445x over previous
//
#include <hip/hip_runtime.h>
#include <hip/hip_bf16.h>

// ---------------------------------------------------------------------------
// RWKV TimeMix:  k = x Wk^T ; r = x Wr^T ; v = r ; y = wkv(w,u,k,v)
//                out = (sigmoid(r) * y) Wo^T
// B=16, T=1024, C=1024.  All inputs and the output are FLOAT32.
//
// Pipeline: cast x/Wk/Wr/Wo to bf16; fused kr-GEMM (N=2048, Wk|Wr split) via
// bf16 MFMA + global_load_lds staging (m97 rung); fp32 log2-domain scan with
// 8-deep register prefetch; final GEMM with fp32 epilogue.
//
// Memory plan:
//   ws:    [xb 32 MiB][Wkb 2][Wrb 2][Wob 2]  (38 MiB; sy reuses xb slot)
//   d_out: 64 MiB fp32 — mid-pipeline holds kr bf16 [M, 2C] (k cols 0..C-1,
//          r cols C..2C-1); finally overwritten with fp32 out (gemm3 reads
//          sy from ws, so it never reads what it writes).
// ---------------------------------------------------------------------------

typedef __attribute__((ext_vector_type(8))) short bf16x8;   // 8 bf16 = 4 VGPRs
typedef __attribute__((ext_vector_type(4))) float f32x4;    // MFMA C/D
typedef __attribute__((ext_vector_type(4))) unsigned int u32x4;
typedef unsigned short u16;

#define BM 128
#define BN 128
#define BK 32

__device__ __forceinline__ void async_copy16(const void* g, void* l) {
    __builtin_amdgcn_global_load_lds(
        (const __attribute__((address_space(1))) void*)g,
        (__attribute__((address_space(3))) void*)l,
        16 /*bytes*/, 0 /*offset*/, 0 /*aux*/);
}

// ---- fp32 -> bf16 cast, 4 elements/thread ---------------------------------
__global__ __launch_bounds__(256) void cast_f32_bf16_kernel(
    const float* __restrict__ src, __hip_bfloat16* __restrict__ dst, int n)
{
    const int i = (blockIdx.x * 256 + threadIdx.x) * 4;
    if (i + 3 < n) {
        const f32x4 v = *(const f32x4*)(src + i);
        __hip_bfloat16 o[4];
        o[0] = __float2bfloat16(v[0]);
        o[1] = __float2bfloat16(v[1]);
        o[2] = __float2bfloat16(v[2]);
        o[3] = __float2bfloat16(v[3]);
        *(__attribute__((ext_vector_type(4))) short*)(dst + i) =
            *(__attribute__((ext_vector_type(4))) short*)o;
    }
}

// ---- C[m, bn+n] = sum_k A[m,k] * Bt[n,k] ----------------------------------
// Bt row-major [N,K] == B transposed.  Bt source = B0 for n < nsplit, else
// B1 (rows n-nsplit).  Staging via global_load_lds width=16 (m97 pattern:
// per-wave LDS dest = uniform base + lane*16).
template <typename OutT>
__global__ __launch_bounds__(256) void gemm_bt_kernel(
    const __hip_bfloat16* __restrict__ A,
    const __hip_bfloat16* __restrict__ B0,
    const __hip_bfloat16* __restrict__ B1,
    OutT* __restrict__ C,
    int K, int ldc, int nsplit)
{
    __shared__ __align__(16) __hip_bfloat16 As[BM * BK];   // 8 KiB
    __shared__ __align__(16) __hip_bfloat16 Bs[BN * BK];   // 8 KiB

    const int tid = threadIdx.x;
    const int bm  = blockIdx.x * BM;
    const int bn  = blockIdx.y * BN;

    const __hip_bfloat16* Bsrc;
    int bnl;
    if (bn < nsplit) { Bsrc = B0; bnl = bn; }
    else             { Bsrc = B1; bnl = bn - nsplit; }

    const int wave = tid >> 6;
    const int lane = tid & 63;
    const int wm   = (wave & 1) * 64;
    const int wn   = (wave >> 1) * 64;
    const int nl   = lane & 15;
    const int quad = lane >> 4;

    f32x4 acc[4][4] = {};

    // LDS tile row-major [128][32] bf16 (row = 64 B) = 2 chunks of 4 KiB.
    // Thread tid owns 16 B at offsets o0 = tid*16 (rows 0..63) and o0+4096
    // (rows 64..127); per wave that is uniform base + lane*16.
    const int o0 = tid * 16;
    const int o1 = o0 + 4096;
    const int rA0 = o0 >> 6, cA0 = o0 & 63;   // row, byte-in-row
    const int rA1 = o1 >> 6, cA1 = o1 & 63;

    const size_t rowb = (size_t)K * 2;
    const char* Ag0 = (const char*)A    + (size_t)(bm + rA0) * rowb + cA0;
    const char* Ag1 = (const char*)A    + (size_t)(bm + rA1) * rowb + cA1;
    const char* Bg0 = (const char*)Bsrc + (size_t)(bnl + rA0) * rowb + cA0;
    const char* Bg1 = (const char*)Bsrc + (size_t)(bnl + rA1) * rowb + cA1;

    for (int kt = 0; kt < K; kt += BK) {
        __syncthreads();  // previous iteration's LDS reads complete
        {
            const size_t kb = (size_t)kt * 2;
            async_copy16(Ag0 + kb, (char*)As + o0);
            async_copy16(Ag1 + kb, (char*)As + o1);
            async_copy16(Bg0 + kb, (char*)Bs + o0);
            async_copy16(Bg1 + kb, (char*)Bs + o1);
        }
        __syncthreads();  // compiler drains vmcnt before s_barrier

        const __hip_bfloat16* Ab = As + (wm + nl) * BK + quad * 8;
        const __hip_bfloat16* Bb = Bs + (wn + nl) * BK + quad * 8;
        bf16x8 af[4], bfr[4];
#pragma unroll
        for (int i = 0; i < 4; ++i) af[i]  = *(const bf16x8*)(Ab + i * 16 * BK);
#pragma unroll
        for (int j = 0; j < 4; ++j) bfr[j] = *(const bf16x8*)(Bb + j * 16 * BK);
#pragma unroll
        for (int i = 0; i < 4; ++i)
#pragma unroll
            for (int j = 0; j < 4; ++j)
                acc[i][j] = __builtin_amdgcn_mfma_f32_16x16x32_bf16(
                    af[i], bfr[j], acc[i][j], 0, 0, 0);
    }

    // C/D layout (m89-verified): col = lane&15, row = quad*4 + reg.
#pragma unroll
    for (int i = 0; i < 4; ++i) {
#pragma unroll
        for (int j = 0; j < 4; ++j) {
            const int n = bn + wn + j * 16 + nl;
#pragma unroll
            for (int r = 0; r < 4; ++r) {
                const int m = bm + wm + i * 16 + quad * 4 + r;
                float vv = acc[i][j][r];
                if constexpr (__is_same(OutT, float))
                    C[(size_t)m * ldc + n] = vv;
                else
                    C[(size_t)m * ldc + n] = __float2bfloat16(vv);
            }
        }
    }
}

// ---------------------------------------------------------------------------
// WKV scan + sigmoid gate.  One thread per (b,c) channel, sequential over T.
// kr interleaved [M, 2C]: k at col c, r(=v) at col C+c.  Output sy [M, C].
// ---------------------------------------------------------------------------
#define L2E 1.4426950408889634f

struct Blk { u16 k[8]; u16 v[8]; };

__device__ __forceinline__ void load8(const u16* kp, const u16* vp,
                                      int t, int S, Blk& B) {
#pragma unroll
    for (int j = 0; j < 8; ++j) {
        B.k[j] = kp[(size_t)(t + j) * S];
        B.v[j] = vp[(size_t)(t + j) * S];
    }
}

__device__ __forceinline__ float bf2f(u16 r) {
    return __uint_as_float(((unsigned)r) << 16);
}

__device__ __forceinline__ void wkv_step(
    u16 kraw, u16 vraw, float u2, float w2,
    float& a, float& bb, float& pp2, __hip_bfloat16* op)
{
    const float kf = bf2f(kraw);
    const float vf = bf2f(vraw);
    const float k2 = kf * L2E;

    // output: y = (e1*a + e2*v)/(e1*bb + e2), divided through by e2 (q cancels)
    const float ww2 = u2 + k2;
    const float s   = __builtin_amdgcn_exp2f(fminf(pp2 - ww2, 60.f));
    const float num = s * a + vf;
    const float den = s * bb + 1.f;
    // gate: sigmoid(v) folded into a single reciprocal
    const float e   = __builtin_amdgcn_exp2f(-L2E * vf);
    const float res = num * __builtin_amdgcn_rcpf(den * (1.f + e));
    *op = __float2bfloat16(res);

    // state: d=(pp+w)-k (log2); e1b=2^min(d,0), e2b=2^(min(d,0)-d)
    const float d   = pp2 + w2 - k2;
    const float m0  = fminf(d, 0.f);
    const float e1b = __builtin_amdgcn_exp2f(m0);
    const float e2b = __builtin_amdgcn_exp2f(m0 - d);
    a   = e1b * a  + e2b * vf;
    bb  = e1b * bb + e2b;
    pp2 = k2 + fmaxf(d, 0.f);
}

__global__ __launch_bounds__(64) void wkv_scan_kernel(
    const __hip_bfloat16* __restrict__ kr,   // [M, 2C] bf16: k | r
    const float* __restrict__ tf,            // time_first (= u)
    const float* __restrict__ td,            // time_decay; w = -exp(td)
    __hip_bfloat16* __restrict__ sy,         // out: sigmoid(r)*y, [M, C]
    int T, int C)
{
    const int gid = blockIdx.x * 64 + threadIdx.x;   // 0 .. B*C-1
    const int b = gid / C;
    const int c = gid - b * C;
    const int S = 2 * C;                             // kr row stride

    const float u2 = tf[c] * L2E;
    const float w2 = -__expf(td[c]) * L2E;

    float a = 0.f, bb = 0.f, pp2 = -1.4427e38f;

    const u16* kp = (const u16*)(kr + (size_t)b * T * S + c);
    const u16* vp = kp + C;
    __hip_bfloat16* op = sy + (size_t)b * T * C + c;

    Blk A, Bq;
    load8(kp, vp, 0, S, A);

    for (int tb = 0; tb < T; tb += 16) {
        load8(kp, vp, tb + 8, S, Bq);       // prefetch next 8 (always valid)
#pragma unroll
        for (int j = 0; j < 8; ++j)
            wkv_step(A.k[j], A.v[j], u2, w2, a, bb, pp2,
                     op + (size_t)(tb + j) * C);
        if (tb + 16 < T) load8(kp, vp, tb + 16, S, A);
#pragma unroll
        for (int j = 0; j < 8; ++j)
            wkv_step(Bq.k[j], Bq.v[j], u2, w2, a, bb, pp2,
                     op + (size_t)(tb + 8 + j) * C);
    }
}

extern "C" void kernel_launch(void* const* d_in, const int* in_sizes, int n_in,
                              void* d_out, int out_size, void* d_ws, size_t ws_size,
                              hipStream_t stream) {
    const float* x  = (const float*)d_in[0];
    const float* Wk = (const float*)d_in[1];
    const float* Wr = (const float*)d_in[2];
    const float* Wo = (const float*)d_in[3];
    const float* td = (const float*)d_in[4];
    const float* tf = (const float*)d_in[5];
    float* out = (float*)d_out;

    const int B = 16, T = 1024, C = 1024;
    const int M = B * T;                       // 16384
    const int MC = M * C;                      // 16,777,216
    const int CC = C * C;                      // 1,048,576

    // ws layout (bf16): xb [MC] | Wkb [CC] | Wrb [CC] | Wob [CC]   (38 MiB)
    __hip_bfloat16* xb  = (__hip_bfloat16*)d_ws;
    __hip_bfloat16* Wkb = xb + (size_t)MC;
    __hip_bfloat16* Wrb = Wkb + (size_t)CC;
    __hip_bfloat16* Wob = Wrb + (size_t)CC;
    __hip_bfloat16* sy  = xb;                  // reuses xb slot (xb dead)

    // d_out mid-pipeline: kr bf16 [M, 2C]
    __hip_bfloat16* kr = (__hip_bfloat16*)d_out;

    // 1) casts fp32 -> bf16
    cast_f32_bf16_kernel<<<MC / 1024, 256, 0, stream>>>(x,  xb,  MC);
    cast_f32_bf16_kernel<<<CC / 1024, 256, 0, stream>>>(Wk, Wkb, CC);
    cast_f32_bf16_kernel<<<CC / 1024, 256, 0, stream>>>(Wr, Wrb, CC);
    cast_f32_bf16_kernel<<<CC / 1024, 256, 0, stream>>>(Wo, Wob, CC);

    // 2) fused kr GEMM: kr[m, 0:C] = xb Wkb^T, kr[m, C:2C] = xb Wrb^T
    gemm_bt_kernel<__hip_bfloat16>
        <<<dim3(M / BM, (2 * C) / BN), 256, 0, stream>>>(
            xb, Wkb, Wrb, kr, C, 2 * C, C);

    // 3) scan + gate -> sy (ws, xb slot)
    wkv_scan_kernel<<<dim3((B * C) / 64), 64, 0, stream>>>(
        kr, tf, td, sy, T, C);

    // 4) out = sy Wob^T -> d_out as fp32 (overwrites kr; sy lives in ws)
    gemm_bt_kernel<float><<<dim3(M / BM, C / BN), 256, 0, stream>>>(
        sy, Wob, Wob, out, C, C, C);
}